// Round 10
// baseline (198.481 us; speedup 1.0000x reference)
//
#include <hip/hip_runtime.h>

#define PHH 7
#define PWW 7
static constexpr float SPATIAL_SCALE = 0.0625f;

// Antiderivative of hat function phi(t) = max(0, 1-|t|), saturating to [0,1].
__device__ __forceinline__ float hat_int(float t) {
    t = fminf(fmaxf(t, -1.0f), 1.0f);
    float a = t + 1.0f, b = 1.0f - t;
    return (t <= 0.0f) ? 0.5f * a * a : 1.0f - 0.5f * b * b;
}

// Exact 1D integral of the hat basis at grid node g over [lo, hi].
__device__ __forceinline__ float bin_w(float lo, float hi, float g) {
    return hat_int(hi - g) - hat_int(lo - g);
}

__device__ __forceinline__ unsigned short f32_to_bf16_rne(float x) {
    unsigned int u = __float_as_uint(x);
    unsigned int r = 0x7FFFu + ((u >> 16) & 1u);
    return (unsigned short)((u + r) >> 16);
}

__device__ __forceinline__ float bf_lo(unsigned int v) {
    return __uint_as_float(v << 16);
}
__device__ __forceinline__ float bf_hi(unsigned int v) {
    return __uint_as_float(v & 0xFFFF0000u);
}

// NCHW f32 -> NHWC bf16 transpose, 64x64 tiles. Reads 4B/lane coalesced,
// writes packed uint (2 bf16 channels) = 4B/lane coalesced.
__global__ __launch_bounds__(256) void transpose_nchw_nhwc_bf16_v2(
    const float* __restrict__ src, unsigned short* __restrict__ dst,
    int C, int HW)
{
    __shared__ unsigned short tile[64][66];
    const int n = blockIdx.z;
    const int hw0 = blockIdx.x * 64;
    const int c0 = blockIdx.y * 64;
    const float* s = src + (size_t)n * C * HW;
    unsigned short* d = dst + (size_t)n * C * HW;

    const int tx = threadIdx.x & 63;   // hw lane
    const int ty = threadIdx.x >> 6;   // 0..3
    #pragma unroll
    for (int i = 0; i < 16; ++i) {
        const int cl = ty * 16 + i;
        const int c = c0 + cl, hw = hw0 + tx;
        if (c < C && hw < HW)
            tile[cl][tx] = f32_to_bf16_rne(s[(size_t)c * HW + hw]);
    }
    __syncthreads();

    const int cl = threadIdx.x & 31;   // c-pair index 0..31
    const int hb = threadIdx.x >> 5;   // 0..7
    #pragma unroll
    for (int i = 0; i < 8; ++i) {
        const int hwl = hb * 8 + i;
        const int hw = hw0 + hwl;
        const int c = c0 + 2 * cl;
        if (hw < HW && c < C) {
            const unsigned int v = (unsigned int)tile[2 * cl][hwl]
                                 | ((unsigned int)tile[2 * cl + 1][hwl] << 16);
            *(unsigned int*)(d + (size_t)hw * C + c) = v;
        }
    }
}

// One block per (roi, p-bin, ch-half): 7168 fine-grained blocks (halved
// straggler size vs r8; HW dispatcher load-balances at block granularity —
// r9 proved a SW queue only destroys locality). XCD-swizzled so one roi's
// 14 blocks share an XCD's L2 (read reuse + write merging; r9 regression
// showed 2x on both without it). 128 threads = 2 waves splitting column
// chunks; lane = uint = 2 bf16 channels (wave covers the 128-ch half).
// y-contraction first (u = sum_h wy*f), wx applied once per column; depth-3
// row prefetch keeps 16 loads in flight; 1-partial LDS reduce.
__global__ __launch_bounds__(128, 6) void prroi_pool_ch(
    const unsigned short* __restrict__ ft,  // [N, H, W, 256] bf16
    const float* __restrict__ rois,         // [R, 5]
    float* __restrict__ out,                // [R, 256, PHH, PWW]
    int H, int W, int R)
{
    const int nwg = R * PHH * 2;
    int task = (int)blockIdx.x;
    if ((nwg & 7) == 0) {
        const int cpx = nwg >> 3;
        task = (task & 7) * cpx + (task >> 3);
    }
    const int r = task / (PHH * 2);
    const int rem = task % (PHH * 2);
    const int p = rem >> 1;
    const int chHalf = rem & 1;

    const int tid = threadIdx.x;
    const int colWave = tid >> 6;   // 0 or 1
    const int lane = tid & 63;
    const int c0 = chHalf * 128 + lane * 2;

    const float* roi = rois + (size_t)r * 5;
    const int b = (int)roi[0];
    const float x1 = roi[1] * SPATIAL_SCALE;
    const float y1 = roi[2] * SPATIAL_SCALE;
    const float x2 = roi[3] * SPATIAL_SCALE;
    const float y2 = roi[4] * SPATIAL_SCALE;
    const float bw = fmaxf(x2 - x1, 0.0f) / (float)PWW;
    const float bh = fmaxf(y2 - y1, 0.0f) / (float)PHH;
    const float area = bw * bh;
    const float inv_area = (area > 0.0f) ? 1.0f / fmaxf(area, 1e-12f) : 0.0f;

    const float ylo = y1 + (float)p * bh;
    const float yhi = ylo + bh;
    const int h0 = max(0, (int)ceilf(ylo - 1.0f));
    const int h1 = min(H - 1, (int)floorf(yhi + 1.0f));
    const int w0 = max(0, (int)ceilf(x1 - 1.0f));
    const int w1 = min(W - 1, (int)floorf(x2 + 1.0f));
    const int nh = min(h1 - h0 + 1, 16);  // p-bin spans <= bh+3 ~ 10 rows
    const int ww = w1 - w0 + 1;           // <= W (152)
    const int wwpad = (ww + 7) & ~7;

    __shared__ float wx8[152 * 8];   // [wi][q] (slot 7 = 0), inv_area folded
    __shared__ float wys[16];
    __shared__ float rbuf[64 * 15];  // stride 15 (odd): conflict-free reduce

    for (int i = tid; i < wwpad; i += 128) {
        const float g = (float)(w0 + i);
        #pragma unroll
        for (int q = 0; q < PWW; ++q) {
            const float lo = x1 + (float)q * bw;
            wx8[i * 8 + q] = (i < ww) ? bin_w(lo, lo + bw, g) * inv_area : 0.0f;
        }
        wx8[i * 8 + 7] = 0.0f;
    }
    for (int i = tid; i < nh; i += 128)
        wys[i] = bin_w(ylo, yhi, (float)(h0 + i));
    __syncthreads();

    float acc[PWW][2];
    #pragma unroll
    for (int q = 0; q < PWW; ++q) { acc[q][0] = 0.0f; acc[q][1] = 0.0f; }

    const size_t rowstride = (size_t)W * 256;  // u16 elements
    const unsigned short* base =
        ft + ((size_t)b * H + (size_t)h0) * rowstride + (size_t)w0 * 256 + c0;

    for (int chunk = colWave * 8; chunk < ww; chunk += 16) {
        int off[8];
        #pragma unroll
        for (int j = 0; j < 8; ++j)
            off[j] = (chunk + j < ww) ? (chunk + j) * 256 : 0;

        float u[2][8];
        #pragma unroll
        for (int j = 0; j < 8; ++j) { u[0][j] = 0.0f; u[1][j] = 0.0f; }

        auto load_row = [&](unsigned int (&v)[8], int i) {
            const unsigned short* rp = base + (size_t)i * rowstride;
            #pragma unroll
            for (int j = 0; j < 8; ++j)
                v[j] = *(const unsigned int*)(rp + off[j]);
        };
        auto fma_row = [&](const unsigned int (&v)[8], float wy) {
            #pragma unroll
            for (int j = 0; j < 8; ++j) {
                u[0][j] = fmaf(wy, bf_lo(v[j]), u[0][j]);
                u[1][j] = fmaf(wy, bf_hi(v[j]), u[1][j]);
            }
        };

        // Depth-3 rotation: rows i+1 and i+2 (16 loads) in flight during
        // each fma_row (r8's 1-deep ping-pong exposed ~1 full latency / 2 rows).
        unsigned int A[8], B[8], C[8];
        load_row(A, 0);
        if (nh > 1) load_row(B, 1);
        int i = 0;
        while (true) {
            if (i + 2 < nh) load_row(C, i + 2);
            fma_row(A, wys[i]);
            if (++i >= nh) break;
            if (i + 2 < nh) load_row(A, i + 2);
            fma_row(B, wys[i]);
            if (++i >= nh) break;
            if (i + 2 < nh) load_row(B, i + 2);
            fma_row(C, wys[i]);
            if (++i >= nh) break;
        }

        // Apply wx once per column (this wave owns the column fully).
        #pragma unroll
        for (int j = 0; j < 8; ++j) {
            const float4 wa = *(const float4*)&wx8[(chunk + j) * 8];
            const float4 wb = *(const float4*)&wx8[(chunk + j) * 8 + 4];
            acc[0][0] = fmaf(wa.x, u[0][j], acc[0][0]);
            acc[0][1] = fmaf(wa.x, u[1][j], acc[0][1]);
            acc[1][0] = fmaf(wa.y, u[0][j], acc[1][0]);
            acc[1][1] = fmaf(wa.y, u[1][j], acc[1][1]);
            acc[2][0] = fmaf(wa.z, u[0][j], acc[2][0]);
            acc[2][1] = fmaf(wa.z, u[1][j], acc[2][1]);
            acc[3][0] = fmaf(wa.w, u[0][j], acc[3][0]);
            acc[3][1] = fmaf(wa.w, u[1][j], acc[3][1]);
            acc[4][0] = fmaf(wb.x, u[0][j], acc[4][0]);
            acc[4][1] = fmaf(wb.x, u[1][j], acc[4][1]);
            acc[5][0] = fmaf(wb.y, u[0][j], acc[5][0]);
            acc[5][1] = fmaf(wb.y, u[1][j], acc[5][1]);
            acc[6][0] = fmaf(wb.z, u[0][j], acc[6][0]);
            acc[6][1] = fmaf(wb.z, u[1][j], acc[6][1]);
        }
    }

    // 2-partial reduce: wave 1 writes, one barrier, wave 0 adds + stores.
    float* pbuf = rbuf + lane * 15;
    if (colWave == 1) {
        #pragma unroll
        for (int q = 0; q < PWW; ++q) {
            pbuf[q * 2 + 0] = acc[q][0];
            pbuf[q * 2 + 1] = acc[q][1];
        }
    }
    __syncthreads();
    if (colWave == 0) {
        float* o = out + ((size_t)r * 256 + c0) * (PHH * PWW) + p * PWW;
        #pragma unroll
        for (int q = 0; q < PWW; ++q) {
            o[q]             = acc[q][0] + pbuf[q * 2 + 0];
            o[PHH * PWW + q] = acc[q][1] + pbuf[q * 2 + 1];
        }
    }
}

// Fallback (no scratch): one thread per output element, reads NCHW directly.
__global__ __launch_bounds__(256) void prroi_pool_nchw(
    const float* __restrict__ f, const float* __restrict__ rois,
    float* __restrict__ out, int C, int H, int W, int R)
{
    const int idx = blockIdx.x * blockDim.x + threadIdx.x;
    const int total = R * C * PHH * PWW;
    if (idx >= total) return;
    const int q = idx % PWW;
    const int p = (idx / PWW) % PHH;
    const int c = (idx / (PWW * PHH)) % C;
    const int r = idx / (PWW * PHH * C);
    const float* roi = rois + (size_t)r * 5;
    const int b = (int)roi[0];
    const float x1 = roi[1] * SPATIAL_SCALE;
    const float y1 = roi[2] * SPATIAL_SCALE;
    const float x2 = roi[3] * SPATIAL_SCALE;
    const float y2 = roi[4] * SPATIAL_SCALE;
    const float bw = fmaxf(x2 - x1, 0.0f) / (float)PWW;
    const float bh = fmaxf(y2 - y1, 0.0f) / (float)PHH;
    const float area = bw * bh;
    const float inv_area = (area > 0.0f) ? 1.0f / fmaxf(area, 1e-12f) : 0.0f;
    const float xlo = x1 + (float)q * bw, xhi = xlo + bw;
    const float ylo = y1 + (float)p * bh, yhi = ylo + bh;
    const int h0 = max(0, (int)ceilf(ylo - 1.0f));
    const int h1 = min(H - 1, (int)floorf(yhi + 1.0f));
    const int w0 = max(0, (int)ceilf(xlo - 1.0f));
    const int w1 = min(W - 1, (int)floorf(xhi + 1.0f));
    float acc = 0.0f;
    for (int h = h0; h <= h1; ++h) {
        const float wy = bin_w(ylo, yhi, (float)h);
        const float* fr = f + (((size_t)b * C + c) * H + h) * W;
        for (int w = w0; w <= w1; ++w)
            acc = fmaf(wy * bin_w(xlo, xhi, (float)w), fr[w], acc);
    }
    out[idx] = acc * inv_area;
}

extern "C" void kernel_launch(void* const* d_in, const int* in_sizes, int n_in,
                              void* d_out, int out_size, void* d_ws, size_t ws_size,
                              hipStream_t stream)
{
    const float* features = (const float*)d_in[0];
    const float* rois = (const float*)d_in[1];
    float* out = (float*)d_out;

    const int C = 256, H = 152, W = 152;
    const int N = in_sizes[0] / (C * H * W);
    const int R = in_sizes[1] / 5;

    const size_t need = (size_t)N * C * H * W * sizeof(unsigned short);
    if (ws_size >= need && C == 256) {
        unsigned short* ft = (unsigned short*)d_ws;
        const int HW = H * W;
        dim3 tgrid((HW + 63) / 64, (C + 63) / 64, N);
        transpose_nchw_nhwc_bf16_v2<<<tgrid, 256, 0, stream>>>(features, ft, C, HW);
        prroi_pool_ch<<<R * PHH * 2, 128, 0, stream>>>(ft, rois, out, H, W, R);
    } else {
        const int total = R * C * PHH * PWW;
        prroi_pool_nchw<<<(total + 255) / 256, 256, 0, stream>>>(features, rois, out, C, H, W, R);
    }
}

// Round 11
// 56.547 us; speedup vs baseline: 3.5100x; 3.5100x over previous
//
#include <hip/hip_runtime.h>

#define PHH 7
#define PWW 7
static constexpr float SPATIAL_SCALE = 0.0625f;

// Antiderivative of hat function phi(t) = max(0, 1-|t|), saturating to [0,1].
__device__ __forceinline__ float hat_int(float t) {
    t = fminf(fmaxf(t, -1.0f), 1.0f);
    float a = t + 1.0f, b = 1.0f - t;
    return (t <= 0.0f) ? 0.5f * a * a : 1.0f - 0.5f * b * b;
}

// Exact 1D integral of the hat basis at grid node g over [lo, hi].
__device__ __forceinline__ float bin_w(float lo, float hi, float g) {
    return hat_int(hi - g) - hat_int(lo - g);
}

__device__ __forceinline__ unsigned short f32_to_bf16_rne(float x) {
    unsigned int u = __float_as_uint(x);
    unsigned int r = 0x7FFFu + ((u >> 16) & 1u);
    return (unsigned short)((u + r) >> 16);
}

__device__ __forceinline__ float bf_lo(unsigned int v) {
    return __uint_as_float(v << 16);
}
__device__ __forceinline__ float bf_hi(unsigned int v) {
    return __uint_as_float(v & 0xFFFF0000u);
}

// NCHW f32 -> NHWC bf16 transpose, 64x64 tiles. Reads 4B/lane coalesced,
// writes packed uint (2 bf16 channels) = 4B/lane coalesced.
__global__ __launch_bounds__(256) void transpose_nchw_nhwc_bf16_v2(
    const float* __restrict__ src, unsigned short* __restrict__ dst,
    int C, int HW)
{
    __shared__ unsigned short tile[64][66];
    const int n = blockIdx.z;
    const int hw0 = blockIdx.x * 64;
    const int c0 = blockIdx.y * 64;
    const float* s = src + (size_t)n * C * HW;
    unsigned short* d = dst + (size_t)n * C * HW;

    const int tx = threadIdx.x & 63;   // hw lane
    const int ty = threadIdx.x >> 6;   // 0..3
    #pragma unroll
    for (int i = 0; i < 16; ++i) {
        const int cl = ty * 16 + i;
        const int c = c0 + cl, hw = hw0 + tx;
        if (c < C && hw < HW)
            tile[cl][tx] = f32_to_bf16_rne(s[(size_t)c * HW + hw]);
    }
    __syncthreads();

    const int cl = threadIdx.x & 31;   // c-pair index 0..31
    const int hb = threadIdx.x >> 5;   // 0..7
    #pragma unroll
    for (int i = 0; i < 8; ++i) {
        const int hwl = hb * 8 + i;
        const int hw = hw0 + hwl;
        const int c = c0 + 2 * cl;
        if (hw < HW && c < C) {
            const unsigned int v = (unsigned int)tile[2 * cl][hwl]
                                 | ((unsigned int)tile[2 * cl + 1][hwl] << 16);
            *(unsigned int*)(d + (size_t)hw * C + c) = v;
        }
    }
}

// One block per (roi, p-bin, ch-half): 7168 fine-grained blocks, XCD-swizzled
// (one roi's 14 blocks share an XCD's L2 -> read reuse + write merging).
// 128 threads = 2 waves splitting column chunks; lane = uint = 2 bf16 ch.
// y-contraction first, wx once per column; depth-3 row prefetch.
// r10 LESSON: __launch_bounds__(128,6) forced VGPR=40 -> scratch spills ->
// 830 MB HBM traffic, 190 us. Min-waves arg must never squeeze below the
// working set (~26 prefetch + 16 u + 14 acc VGPRs). (128,4) caps at 128 VGPR.
__global__ __launch_bounds__(128, 4) void prroi_pool_ch(
    const unsigned short* __restrict__ ft,  // [N, H, W, 256] bf16
    const float* __restrict__ rois,         // [R, 5]
    float* __restrict__ out,                // [R, 256, PHH, PWW]
    int H, int W, int R)
{
    const int nwg = R * PHH * 2;
    int task = (int)blockIdx.x;
    if ((nwg & 7) == 0) {
        const int cpx = nwg >> 3;
        task = (task & 7) * cpx + (task >> 3);
    }
    const int r = task / (PHH * 2);
    const int rem = task % (PHH * 2);
    const int p = rem >> 1;
    const int chHalf = rem & 1;

    const int tid = threadIdx.x;
    const int colWave = tid >> 6;   // 0 or 1
    const int lane = tid & 63;
    const int c0 = chHalf * 128 + lane * 2;

    const float* roi = rois + (size_t)r * 5;
    const int b = (int)roi[0];
    const float x1 = roi[1] * SPATIAL_SCALE;
    const float y1 = roi[2] * SPATIAL_SCALE;
    const float x2 = roi[3] * SPATIAL_SCALE;
    const float y2 = roi[4] * SPATIAL_SCALE;
    const float bw = fmaxf(x2 - x1, 0.0f) / (float)PWW;
    const float bh = fmaxf(y2 - y1, 0.0f) / (float)PHH;
    const float area = bw * bh;
    const float inv_area = (area > 0.0f) ? 1.0f / fmaxf(area, 1e-12f) : 0.0f;

    const float ylo = y1 + (float)p * bh;
    const float yhi = ylo + bh;
    const int h0 = max(0, (int)ceilf(ylo - 1.0f));
    const int h1 = min(H - 1, (int)floorf(yhi + 1.0f));
    const int w0 = max(0, (int)ceilf(x1 - 1.0f));
    const int w1 = min(W - 1, (int)floorf(x2 + 1.0f));
    const int nh = min(h1 - h0 + 1, 16);  // p-bin spans <= bh+3 ~ 10 rows
    const int ww = w1 - w0 + 1;           // <= W (152)
    const int wwpad = (ww + 7) & ~7;

    __shared__ float wx8[152 * 8];   // [wi][q] (slot 7 = 0), inv_area folded
    __shared__ float wys[16];
    __shared__ float rbuf[64 * 15];  // stride 15 (odd): conflict-free reduce

    for (int i = tid; i < wwpad; i += 128) {
        const float g = (float)(w0 + i);
        #pragma unroll
        for (int q = 0; q < PWW; ++q) {
            const float lo = x1 + (float)q * bw;
            wx8[i * 8 + q] = (i < ww) ? bin_w(lo, lo + bw, g) * inv_area : 0.0f;
        }
        wx8[i * 8 + 7] = 0.0f;
    }
    for (int i = tid; i < nh; i += 128)
        wys[i] = bin_w(ylo, yhi, (float)(h0 + i));
    __syncthreads();

    float acc[PWW][2];
    #pragma unroll
    for (int q = 0; q < PWW; ++q) { acc[q][0] = 0.0f; acc[q][1] = 0.0f; }

    const size_t rowstride = (size_t)W * 256;  // u16 elements
    const unsigned short* base =
        ft + ((size_t)b * H + (size_t)h0) * rowstride + (size_t)w0 * 256 + c0;

    for (int chunk = colWave * 8; chunk < ww; chunk += 16) {
        int off[8];
        #pragma unroll
        for (int j = 0; j < 8; ++j)
            off[j] = (chunk + j < ww) ? (chunk + j) * 256 : 0;

        float u[2][8];
        #pragma unroll
        for (int j = 0; j < 8; ++j) { u[0][j] = 0.0f; u[1][j] = 0.0f; }

        auto load_row = [&](unsigned int (&v)[8], int i) {
            const unsigned short* rp = base + (size_t)i * rowstride;
            #pragma unroll
            for (int j = 0; j < 8; ++j)
                v[j] = *(const unsigned int*)(rp + off[j]);
        };
        auto fma_row = [&](const unsigned int (&v)[8], float wy) {
            #pragma unroll
            for (int j = 0; j < 8; ++j) {
                u[0][j] = fmaf(wy, bf_lo(v[j]), u[0][j]);
                u[1][j] = fmaf(wy, bf_hi(v[j]), u[1][j]);
            }
        };

        // Depth-3 rotation: two rows' loads (16) in flight during each fma_row.
        unsigned int A[8], B[8], C[8];
        load_row(A, 0);
        if (nh > 1) load_row(B, 1);
        int i = 0;
        while (true) {
            if (i + 2 < nh) load_row(C, i + 2);
            fma_row(A, wys[i]);
            if (++i >= nh) break;
            if (i + 2 < nh) load_row(A, i + 2);
            fma_row(B, wys[i]);
            if (++i >= nh) break;
            if (i + 2 < nh) load_row(B, i + 2);
            fma_row(C, wys[i]);
            if (++i >= nh) break;
        }

        // Apply wx once per column (this wave owns the column fully).
        #pragma unroll
        for (int j = 0; j < 8; ++j) {
            const float4 wa = *(const float4*)&wx8[(chunk + j) * 8];
            const float4 wb = *(const float4*)&wx8[(chunk + j) * 8 + 4];
            acc[0][0] = fmaf(wa.x, u[0][j], acc[0][0]);
            acc[0][1] = fmaf(wa.x, u[1][j], acc[0][1]);
            acc[1][0] = fmaf(wa.y, u[0][j], acc[1][0]);
            acc[1][1] = fmaf(wa.y, u[1][j], acc[1][1]);
            acc[2][0] = fmaf(wa.z, u[0][j], acc[2][0]);
            acc[2][1] = fmaf(wa.z, u[1][j], acc[2][1]);
            acc[3][0] = fmaf(wa.w, u[0][j], acc[3][0]);
            acc[3][1] = fmaf(wa.w, u[1][j], acc[3][1]);
            acc[4][0] = fmaf(wb.x, u[0][j], acc[4][0]);
            acc[4][1] = fmaf(wb.x, u[1][j], acc[4][1]);
            acc[5][0] = fmaf(wb.y, u[0][j], acc[5][0]);
            acc[5][1] = fmaf(wb.y, u[1][j], acc[5][1]);
            acc[6][0] = fmaf(wb.z, u[0][j], acc[6][0]);
            acc[6][1] = fmaf(wb.z, u[1][j], acc[6][1]);
        }
    }

    // 2-partial reduce: wave 1 writes, one barrier, wave 0 adds + stores.
    float* pbuf = rbuf + lane * 15;
    if (colWave == 1) {
        #pragma unroll
        for (int q = 0; q < PWW; ++q) {
            pbuf[q * 2 + 0] = acc[q][0];
            pbuf[q * 2 + 1] = acc[q][1];
        }
    }
    __syncthreads();
    if (colWave == 0) {
        float* o = out + ((size_t)r * 256 + c0) * (PHH * PWW) + p * PWW;
        #pragma unroll
        for (int q = 0; q < PWW; ++q) {
            o[q]             = acc[q][0] + pbuf[q * 2 + 0];
            o[PHH * PWW + q] = acc[q][1] + pbuf[q * 2 + 1];
        }
    }
}

// Fallback (no scratch): one thread per output element, reads NCHW directly.
__global__ __launch_bounds__(256) void prroi_pool_nchw(
    const float* __restrict__ f, const float* __restrict__ rois,
    float* __restrict__ out, int C, int H, int W, int R)
{
    const int idx = blockIdx.x * blockDim.x + threadIdx.x;
    const int total = R * C * PHH * PWW;
    if (idx >= total) return;
    const int q = idx % PWW;
    const int p = (idx / PWW) % PHH;
    const int c = (idx / (PWW * PHH)) % C;
    const int r = idx / (PWW * PHH * C);
    const float* roi = rois + (size_t)r * 5;
    const int b = (int)roi[0];
    const float x1 = roi[1] * SPATIAL_SCALE;
    const float y1 = roi[2] * SPATIAL_SCALE;
    const float x2 = roi[3] * SPATIAL_SCALE;
    const float y2 = roi[4] * SPATIAL_SCALE;
    const float bw = fmaxf(x2 - x1, 0.0f) / (float)PWW;
    const float bh = fmaxf(y2 - y1, 0.0f) / (float)PHH;
    const float area = bw * bh;
    const float inv_area = (area > 0.0f) ? 1.0f / fmaxf(area, 1e-12f) : 0.0f;
    const float xlo = x1 + (float)q * bw, xhi = xlo + bw;
    const float ylo = y1 + (float)p * bh, yhi = ylo + bh;
    const int h0 = max(0, (int)ceilf(ylo - 1.0f));
    const int h1 = min(H - 1, (int)floorf(yhi + 1.0f));
    const int w0 = max(0, (int)ceilf(xlo - 1.0f));
    const int w1 = min(W - 1, (int)floorf(xhi + 1.0f));
    float acc = 0.0f;
    for (int h = h0; h <= h1; ++h) {
        const float wy = bin_w(ylo, yhi, (float)h);
        const float* fr = f + (((size_t)b * C + c) * H + h) * W;
        for (int w = w0; w <= w1; ++w)
            acc = fmaf(wy * bin_w(xlo, xhi, (float)w), fr[w], acc);
    }
    out[idx] = acc * inv_area;
}

extern "C" void kernel_launch(void* const* d_in, const int* in_sizes, int n_in,
                              void* d_out, int out_size, void* d_ws, size_t ws_size,
                              hipStream_t stream)
{
    const float* features = (const float*)d_in[0];
    const float* rois = (const float*)d_in[1];
    float* out = (float*)d_out;

    const int C = 256, H = 152, W = 152;
    const int N = in_sizes[0] / (C * H * W);
    const int R = in_sizes[1] / 5;

    const size_t need = (size_t)N * C * H * W * sizeof(unsigned short);
    if (ws_size >= need && C == 256) {
        unsigned short* ft = (unsigned short*)d_ws;
        const int HW = H * W;
        dim3 tgrid((HW + 63) / 64, (C + 63) / 64, N);
        transpose_nchw_nhwc_bf16_v2<<<tgrid, 256, 0, stream>>>(features, ft, C, HW);
        prroi_pool_ch<<<R * PHH * 2, 128, 0, stream>>>(ft, rois, out, H, W, R);
    } else {
        const int total = R * C * PHH * PWW;
        prroi_pool_nchw<<<(total + 255) / 256, 256, 0, stream>>>(features, rois, out, C, H, W, R);
    }
}